// Round 3
// baseline (1007.588 us; speedup 1.0000x reference)
//
#include <hip/hip_runtime.h>
#include <hip/hip_bf16.h>

// Problem constants (fixed by the reference)
constexpr int NN = 50000;      // nodes per type
constexpr int DD = 128;        // feature dim
constexpr int EE = 600000;     // edges per relation
constexpr long long PP = (long long)NN * DD;   // 6,400,000 elems per [N,128] buffer

// ---------------------------------------------------------------------------
// Output is FLOAT32 (reference computes in f32): d_out = [out_user | out_item],
// each [50000,128] f32. d_out doubles as the pre-activation staging buffer.
//
// Workspace layout (floats) — ~28.6 MB total:
//   acc    [PP]        aggregated raw src features for current relation (f32)
//   cnt    [NN] int    per-target edge count (current relation)
//   cursor [NN] int
//   rowst  [NN] int    CSR row starts
//   eidx   [EE] int    CSR column (source) indices
// Relations are processed sequentially so buffers are reused.
//
// Math plan (exact by linearity of segment-mean):
//   mean_edges(x_src @ W) = (mean_edges x_src) @ W
// so we aggregate RAW 128-d features once per relation and project the
// 50000-row aggregate with a single 128x128 GEMM.
// ---------------------------------------------------------------------------

__global__ void hist_kernel(const int* __restrict__ etgt, int* __restrict__ cnt,
                            int nedges) {
    int e = blockIdx.x * blockDim.x + threadIdx.x;
    if (e < nedges) atomicAdd(&cnt[etgt[e]], 1);
}

// Single block, 1024 threads. Per-thread chunk sums -> thread-0 serial scan of
// the 1024 partials in LDS -> per-thread writeback. Deliberately simple.
__global__ void scan_kernel(const int* __restrict__ cnt, int* __restrict__ rowst,
                            int n) {
    __shared__ int tsum[1024];
    const int tid = threadIdx.x;
    const int chunk = (n + 1023) / 1024;
    int i0 = tid * chunk;
    int i1 = i0 + chunk; if (i1 > n) i1 = n;
    int s = 0;
    for (int i = i0; i < i1; ++i) s += cnt[i];
    tsum[tid] = s;
    __syncthreads();
    if (tid == 0) {
        int run = 0;
        for (int t = 0; t < 1024; ++t) { int v = tsum[t]; tsum[t] = run; run += v; }
    }
    __syncthreads();
    int run = tsum[tid];
    for (int i = i0; i < i1; ++i) { rowst[i] = run; run += cnt[i]; }
}

__global__ void place_kernel(const int* __restrict__ esrc, const int* __restrict__ etgt,
                             const int* __restrict__ rowst, int* __restrict__ cursor,
                             int* __restrict__ eidx, int nedges) {
    int e = blockIdx.x * blockDim.x + threadIdx.x;
    if (e >= nedges) return;
    int t = etgt[e];
    int pos = atomicAdd(&cursor[t], 1);
    eidx[rowst[t] + pos] = esrc[e];
}

// One wave per target row: sum raw src rows (float2/lane = 512B/wave, coalesced).
__global__ __launch_bounds__(256) void gather_kernel(
    const float* __restrict__ xsrc, const int* __restrict__ rowst,
    const int* __restrict__ cnt, const int* __restrict__ eidx,
    float* __restrict__ acc, int n) {
    int wv = (int)((blockIdx.x * blockDim.x + threadIdx.x) >> 6);
    int lane = threadIdx.x & 63;
    if (wv >= n) return;
    int start = rowst[wv], deg = cnt[wv];
    float sx = 0.f, sy = 0.f;
    for (int j = 0; j < deg; ++j) {
        int src = eidx[start + j];
        const float2 v = *(const float2*)(xsrc + (size_t)src * DD + lane * 2);
        sx += v.x; sy += v.y;
    }
    float2 o; o.x = sx; o.y = sy;
    *(float2*)(acc + (size_t)wv * DD + lane * 2) = o;
}

// Y[nrows,128] (64-col half per blockIdx.y) = A @ (W1 [+W2]).
// Options: per-row scale 1/max(cnt,1) (cnt!=null); += Yin (Yin!=null);
// if dorelu: store relu(postmul*v) else store v.  All f32.
// LDS: 32KB W-half + 16KB A-tile = 48KB.
__global__ __launch_bounds__(256, 2) void gemm_kernel(
    const float* __restrict__ A, const float* __restrict__ W1,
    const float* __restrict__ W2, const int* __restrict__ cnt,
    const float* __restrict__ Yin, float* __restrict__ Yout,
    float postmul, int dorelu, int nrows) {
    __shared__ float lW[128][64];
    __shared__ float lA[32][128];
    const int c0 = blockIdx.y * 64;
    const int r0 = blockIdx.x * 32;

    for (int idx = threadIdx.x; idx < 128 * 64; idx += 256) {
        int k = idx >> 6, c = idx & 63;
        float w = W1[k * 128 + c0 + c];
        if (W2) w += W2[k * 128 + c0 + c];
        lW[k][c] = w;
    }
    for (int idx = threadIdx.x; idx < 32 * 128; idx += 256) {
        int r = idx >> 7, k = idx & 127;
        int g = r0 + r;
        lA[r][k] = (g < nrows) ? A[(size_t)g * 128 + k] : 0.0f;
    }
    __syncthreads();

    const int c4 = (threadIdx.x & 15) * 4;
    const int rt = threadIdx.x >> 4;   // 0..15
    float a00 = 0, a01 = 0, a02 = 0, a03 = 0;
    float a10 = 0, a11 = 0, a12 = 0, a13 = 0;
    #pragma unroll 8
    for (int k = 0; k < 128; ++k) {
        const float4 w = *(const float4*)&lW[k][c4];
        const float x0 = lA[rt][k];
        const float x1 = lA[rt + 16][k];
        a00 += x0 * w.x; a01 += x0 * w.y; a02 += x0 * w.z; a03 += x0 * w.w;
        a10 += x1 * w.x; a11 += x1 * w.y; a12 += x1 * w.z; a13 += x1 * w.w;
    }

    #pragma unroll
    for (int rr = 0; rr < 2; ++rr) {
        int r = rt + rr * 16;
        int g = r0 + r;
        if (g >= nrows) continue;
        float sc = 1.0f;
        if (cnt) { int cc = cnt[g]; sc = 1.0f / (float)(cc > 1 ? cc : 1); }
        float v0 = (rr ? a10 : a00) * sc;
        float v1 = (rr ? a11 : a01) * sc;
        float v2 = (rr ? a12 : a02) * sc;
        float v3 = (rr ? a13 : a03) * sc;
        const size_t off = (size_t)g * 128 + c0 + c4;
        if (Yin) { v0 += Yin[off]; v1 += Yin[off + 1]; v2 += Yin[off + 2]; v3 += Yin[off + 3]; }
        if (dorelu) {
            v0 *= postmul; v1 *= postmul; v2 *= postmul; v3 *= postmul;
            v0 = v0 > 0.f ? v0 : 0.f;
            v1 = v1 > 0.f ? v1 : 0.f;
            v2 = v2 > 0.f ? v2 : 0.f;
            v3 = v3 > 0.f ? v3 : 0.f;
        }
        float4 o; o.x = v0; o.y = v1; o.z = v2; o.w = v3;
        *(float4*)(Yout + off) = o;
    }
}

extern "C" void kernel_launch(void* const* d_in, const int* in_sizes, int n_in,
                              void* d_out, int out_size, void* d_ws, size_t ws_size,
                              hipStream_t stream) {
    const float* x_user = (const float*)d_in[0];
    const float* x_item = (const float*)d_in[1];
    const float* w_rates_src   = (const float*)d_in[2];
    const float* w_rates_tgt   = (const float*)d_in[3];
    const float* w_rated_src   = (const float*)d_in[4];
    const float* w_rated_tgt   = (const float*)d_in[5];
    const float* w_follows_src = (const float*)d_in[6];
    const float* w_follows_tgt = (const float*)d_in[7];
    const int* e_rates   = (const int*)d_in[8];    // row0 src(user), row1 tgt(item)
    const int* e_rated   = (const int*)d_in[9];    // row0 src(item), row1 tgt(user)
    const int* e_follows = (const int*)d_in[10];   // row0 src(user), row1 tgt(user)

    float* ws  = (float*)d_ws;
    float* acc = ws;                        // [PP]
    int* cnt    = (int*)(ws + PP);          // [NN]
    int* cursor = cnt + NN;                 // [NN]
    int* rowst  = cnt + 2 * NN;             // [NN]
    int* eidx   = cnt + 3 * NN;             // [EE]

    float* out_user = (float*)d_out;        // [PP] f32 (also staging)
    float* out_item = out_user + PP;        // [PP] f32 (also staging)

    const int EB = (EE + 255) / 256;
    const int GB = (NN + 3) / 4;            // 4 waves/block, 1 row per wave
    const dim3 gg((NN + 31) / 32, 2);

    // ---- relation 'rated_by' (src=item, tgt=user) -> acc
    hipMemsetAsync(cnt, 0, (size_t)2 * NN * sizeof(int), stream);
    hist_kernel<<<EB, 256, 0, stream>>>(e_rated + EE, cnt, EE);
    scan_kernel<<<1, 1024, 0, stream>>>(cnt, rowst, NN);
    place_kernel<<<EB, 256, 0, stream>>>(e_rated, e_rated + EE, rowst, cursor, eidx, EE);
    gather_kernel<<<GB, 256, 0, stream>>>(x_item, rowst, cnt, eidx, acc, NN);

    // out_user(tmp) = x_user @ (w_rated_tgt + w_follows_tgt)
    gemm_kernel<<<gg, 256, 0, stream>>>(x_user, w_rated_tgt, w_follows_tgt,
                                        nullptr, nullptr, out_user, 1.0f, 0, NN);
    // out_user(tmp) += (acc/cnt) @ w_rated_src
    gemm_kernel<<<gg, 256, 0, stream>>>(acc, w_rated_src, nullptr,
                                        cnt, out_user, out_user, 1.0f, 0, NN);

    // ---- relation 'follows' (src=user, tgt=user) -> acc
    hipMemsetAsync(cnt, 0, (size_t)2 * NN * sizeof(int), stream);
    hist_kernel<<<EB, 256, 0, stream>>>(e_follows + EE, cnt, EE);
    scan_kernel<<<1, 1024, 0, stream>>>(cnt, rowst, NN);
    place_kernel<<<EB, 256, 0, stream>>>(e_follows, e_follows + EE, rowst, cursor, eidx, EE);
    gather_kernel<<<GB, 256, 0, stream>>>(x_user, rowst, cnt, eidx, acc, NN);

    // out_user = relu(0.5 * (tmp + (acc/cnt) @ w_follows_src))  [f32, in-place]
    gemm_kernel<<<gg, 256, 0, stream>>>(acc, w_follows_src, nullptr,
                                        cnt, out_user, out_user, 0.5f, 1, NN);

    // ---- relation 'rates' (src=user, tgt=item) -> acc
    hipMemsetAsync(cnt, 0, (size_t)2 * NN * sizeof(int), stream);
    hist_kernel<<<EB, 256, 0, stream>>>(e_rates + EE, cnt, EE);
    scan_kernel<<<1, 1024, 0, stream>>>(cnt, rowst, NN);
    place_kernel<<<EB, 256, 0, stream>>>(e_rates, e_rates + EE, rowst, cursor, eidx, EE);
    gather_kernel<<<GB, 256, 0, stream>>>(x_user, rowst, cnt, eidx, acc, NN);

    // out_item(tmp) = x_item @ w_rates_tgt
    gemm_kernel<<<gg, 256, 0, stream>>>(x_item, w_rates_tgt, nullptr,
                                        nullptr, nullptr, out_item, 1.0f, 0, NN);
    // out_item = relu(tmp + (acc/cnt) @ w_rates_src)  [f32, in-place]
    gemm_kernel<<<gg, 256, 0, stream>>>(acc, w_rates_src, nullptr,
                                        cnt, out_item, out_item, 1.0f, 1, NN);
}

// Round 4
// 646.454 us; speedup vs baseline: 1.5586x; 1.5586x over previous
//
#include <hip/hip_runtime.h>
#include <hip/hip_bf16.h>

constexpr int NN = 50000;      // nodes per type
constexpr int DD = 128;        // feature dim
constexpr int EE = 600000;     // edges per relation
constexpr long long PP = (long long)NN * DD;   // 6,400,000 elems per [N,128]

typedef __bf16 bf16x8 __attribute__((ext_vector_type(8)));
typedef float f32x4 __attribute__((ext_vector_type(4)));

__device__ inline unsigned short f2bs(float x) {
    __hip_bfloat16 b = __float2bfloat16(x);
    return *reinterpret_cast<unsigned short*>(&b);
}
__device__ inline float bs2f(unsigned short u) {
    union { float f; unsigned int u; } x; x.u = ((unsigned int)u) << 16; return x.f;
}

// f32 -> bf16 copies of x_user / x_item
__global__ void cvtx_kernel(const float* __restrict__ xu, const float* __restrict__ xi,
                            unsigned short* __restrict__ xub, unsigned short* __restrict__ xib) {
    const int total = (int)(PP / 4);
    for (int i = blockIdx.x * blockDim.x + threadIdx.x; i < total;
         i += gridDim.x * blockDim.x) {
        float4 a = ((const float4*)xu)[i];
        float4 b = ((const float4*)xi)[i];
        ushort4 oa, ob;
        oa.x = f2bs(a.x); oa.y = f2bs(a.y); oa.z = f2bs(a.z); oa.w = f2bs(a.w);
        ob.x = f2bs(b.x); ob.y = f2bs(b.y); ob.z = f2bs(b.z); ob.w = f2bs(b.w);
        ((ushort4*)xub)[i] = oa;
        ((ushort4*)xib)[i] = ob;
    }
}

// Transposed bf16 weights: Wu[n][384] = [Wrt+Wft ; Wrs ; Wfs]^T, Wi[n][256] = [Wit ; Wis]^T
__global__ void wprep_kernel(const float* __restrict__ wrt, const float* __restrict__ wft,
                             const float* __restrict__ wrs, const float* __restrict__ wfs,
                             const float* __restrict__ wit, const float* __restrict__ wis,
                             unsigned short* __restrict__ Wu, unsigned short* __restrict__ Wi) {
    int n = blockIdx.x;   // 0..127
    for (int k = threadIdx.x; k < 384; k += blockDim.x) {
        int seg = k >> 7, ks = k & 127;
        float v = (seg == 0) ? (wrt[ks * 128 + n] + wft[ks * 128 + n])
                : (seg == 1) ? wrs[ks * 128 + n] : wfs[ks * 128 + n];
        Wu[n * 384 + k] = f2bs(v);
    }
    for (int k = threadIdx.x; k < 256; k += blockDim.x) {
        int seg = k >> 7, ks = k & 127;
        float v = (seg == 0) ? wit[ks * 128 + n] : wis[ks * 128 + n];
        Wi[n * 256 + k] = f2bs(v);
    }
}

// histogram over all 3 relations (rel = idx/EE)
__global__ void hist3_kernel(const int* __restrict__ t0, const int* __restrict__ t1,
                             const int* __restrict__ t2, int* __restrict__ cnt) {
    int idx = blockIdx.x * blockDim.x + threadIdx.x;
    if (idx >= 3 * EE) return;
    int rel = idx / EE;
    int e = idx - rel * EE;
    const int* tp = (rel == 0) ? t0 : (rel == 1) ? t1 : t2;
    atomicAdd(&cnt[rel * NN + tp[e]], 1);
}

// single-block exclusive scan over n entries (simple & audited)
__global__ void scan_kernel(const int* __restrict__ cnt, int* __restrict__ rowst, int n) {
    __shared__ int tsum[1024];
    const int tid = threadIdx.x;
    const int chunk = (n + 1023) / 1024;
    int i0 = tid * chunk, i1 = i0 + chunk; if (i1 > n) i1 = n;
    int s = 0;
    for (int i = i0; i < i1; ++i) s += cnt[i];
    tsum[tid] = s;
    __syncthreads();
    if (tid == 0) {
        int run = 0;
        for (int t = 0; t < 1024; ++t) { int v = tsum[t]; tsum[t] = run; run += v; }
    }
    __syncthreads();
    int run = tsum[tid];
    for (int i = i0; i < i1; ++i) { rowst[i] = run; run += cnt[i]; }
}

__global__ void place3_kernel(const int* __restrict__ s0, const int* __restrict__ t0,
                              const int* __restrict__ s1, const int* __restrict__ t1,
                              const int* __restrict__ s2, const int* __restrict__ t2,
                              const int* __restrict__ rowst, int* __restrict__ cursor,
                              int* __restrict__ eidx) {
    int idx = blockIdx.x * blockDim.x + threadIdx.x;
    if (idx >= 3 * EE) return;
    int rel = idx / EE;
    int e = idx - rel * EE;
    const int* tp = (rel == 0) ? t0 : (rel == 1) ? t1 : t2;
    const int* sp = (rel == 0) ? s0 : (rel == 1) ? s1 : s2;
    int t = rel * NN + tp[e];
    int pos = atomicAdd(&cursor[t], 1);
    eidx[rowst[t] + pos] = sp[e];
}

// one wave per (rel,row): mean of bf16 src rows -> bf16 acc row
__global__ __launch_bounds__(256) void gather3_kernel(
    const unsigned short* __restrict__ xub, const unsigned short* __restrict__ xib,
    const int* __restrict__ rowst, const int* __restrict__ cnt,
    const int* __restrict__ eidx, unsigned short* __restrict__ accb) {
    int rr = (int)((blockIdx.x * blockDim.x + threadIdx.x) >> 6);
    int lane = threadIdx.x & 63;
    if (rr >= 3 * NN) return;
    int rel = rr / NN;                      // 0: rated(src=item) 1: follows 2: rates
    const unsigned short* src = (rel == 0) ? xib : xub;
    int start = rowst[rr], deg = cnt[rr];
    float s0 = 0.f, s1 = 0.f;
    for (int j = 0; j < deg; ++j) {
        int sr = eidx[start + j];
        unsigned int v = *(const unsigned int*)(src + (size_t)sr * DD + lane * 2);
        s0 += bs2f((unsigned short)(v & 0xffff));
        s1 += bs2f((unsigned short)(v >> 16));
    }
    float inv = 1.0f / (float)(deg > 1 ? deg : 1);
    unsigned int o = ((unsigned int)f2bs(s1 * inv) << 16) | f2bs(s0 * inv);
    *(unsigned int*)(accb + (size_t)rr * DD + lane * 2) = o;
}

// C[50000,128] = relu(postmul * concat_K(segs) @ Wt^T), bf16 MFMA, f32 out.
// A segs: up to 3 bf16 [NN][128] matrices, K = ksteps*64 (128 per segment).
// Wt: bf16 [128 n][Ktot k]. Tile: BM=128, BN=64, BK=64, 4 waves.
__global__ __launch_bounds__(256) void mfma_gemm_kernel(
    const unsigned short* __restrict__ a0, const unsigned short* __restrict__ a1,
    const unsigned short* __restrict__ a2, const unsigned short* __restrict__ Wt,
    float* __restrict__ outp, float postmul, int ksteps) {
    __shared__ unsigned char lAb[128 * 128];   // [128 rows][64 k] bf16, XOR-swizzled
    __shared__ unsigned char lBb[64 * 128];    // [64 n][64 k] bf16, XOR-swizzled

    const int tid = threadIdx.x;
    const int m0 = blockIdx.x * 128;
    const int n0 = blockIdx.y * 64;
    const int Ktot = ksteps * 64;
    const int wv = tid >> 6, lane = tid & 63;

    f32x4 acc[2][4];
    #pragma unroll
    for (int i = 0; i < 2; ++i)
        #pragma unroll
        for (int j = 0; j < 4; ++j) acc[i][j] = (f32x4)(0.f);

    for (int kt = 0; kt < ksteps; ++kt) {
        const unsigned short* As = (kt >> 1) == 0 ? a0 : (kt >> 1) == 1 ? a1 : a2;
        const int ks0 = (kt & 1) * 64;
        // stage A: 128x64 bf16 = 2048 x 8B units, 8 per thread
        #pragma unroll
        for (int i = 0; i < 8; ++i) {
            int idx = i * 256 + tid;
            int row = idx >> 4, ku = idx & 15;     // 16 units/row
            int g = m0 + row;
            unsigned long long v = 0ull;
            if (g < NN)
                v = *(const unsigned long long*)(As + (size_t)g * DD + ks0 + ku * 4);
            int byte = (row * 128 + ku * 8) ^ ((row & 7) << 4);
            *(unsigned long long*)(lAb + byte) = v;
        }
        // stage B: 64x64 bf16 = 1024 x 8B units, 4 per thread
        #pragma unroll
        for (int i = 0; i < 4; ++i) {
            int idx = i * 256 + tid;
            int n = idx >> 4, ku = idx & 15;
            unsigned long long v =
                *(const unsigned long long*)(Wt + (size_t)(n0 + n) * Ktot + kt * 64 + ku * 4);
            int byte = (n * 128 + ku * 8) ^ ((n & 7) << 4);
            *(unsigned long long*)(lBb + byte) = v;
        }
        __syncthreads();

        #pragma unroll
        for (int kk = 0; kk < 2; ++kk) {           // k-half within BK=64
            bf16x8 af[2], bfr[4];
            #pragma unroll
            for (int mi = 0; mi < 2; ++mi) {
                int row = wv * 32 + mi * 16 + (lane & 15);
                int byte = (row * 128 + kk * 64 + (lane >> 4) * 16) ^ ((row & 7) << 4);
                af[mi] = *(const bf16x8*)(lAb + byte);
            }
            #pragma unroll
            for (int ni = 0; ni < 4; ++ni) {
                int n = ni * 16 + (lane & 15);
                int byte = (n * 128 + kk * 64 + (lane >> 4) * 16) ^ ((n & 7) << 4);
                bfr[ni] = *(const bf16x8*)(lBb + byte);
            }
            #pragma unroll
            for (int mi = 0; mi < 2; ++mi)
                #pragma unroll
                for (int ni = 0; ni < 4; ++ni)
                    acc[mi][ni] = __builtin_amdgcn_mfma_f32_16x16x32_bf16(
                        af[mi], bfr[ni], acc[mi][ni], 0, 0, 0);
        }
        __syncthreads();
    }

    // epilogue: C frag mapping col=lane&15, row=(lane>>4)*4+r  [m89/m91]
    #pragma unroll
    for (int mi = 0; mi < 2; ++mi) {
        #pragma unroll
        for (int ni = 0; ni < 4; ++ni) {
            #pragma unroll
            for (int r = 0; r < 4; ++r) {
                int g = m0 + wv * 32 + mi * 16 + (lane >> 4) * 4 + r;
                if (g < NN) {
                    float v = acc[mi][ni][r] * postmul;
                    outp[(size_t)g * DD + n0 + ni * 16 + (lane & 15)] = v > 0.f ? v : 0.f;
                }
            }
        }
    }
}

extern "C" void kernel_launch(void* const* d_in, const int* in_sizes, int n_in,
                              void* d_out, int out_size, void* d_ws, size_t ws_size,
                              hipStream_t stream) {
    const float* x_user = (const float*)d_in[0];
    const float* x_item = (const float*)d_in[1];
    const float* w_rates_src   = (const float*)d_in[2];
    const float* w_rates_tgt   = (const float*)d_in[3];
    const float* w_rated_src   = (const float*)d_in[4];
    const float* w_rated_tgt   = (const float*)d_in[5];
    const float* w_follows_src = (const float*)d_in[6];
    const float* w_follows_tgt = (const float*)d_in[7];
    const int* e_rates   = (const int*)d_in[8];    // row0 src(user), row1 tgt(item)
    const int* e_rated   = (const int*)d_in[9];    // row0 src(item), row1 tgt(user)
    const int* e_follows = (const int*)d_in[10];   // row0 src(user), row1 tgt(user)

    // ---- workspace carve-up (~73 MB) ----
    char* p = (char*)d_ws;
    unsigned short* xub  = (unsigned short*)p; p += (size_t)PP * 2;
    unsigned short* xib  = (unsigned short*)p; p += (size_t)PP * 2;
    unsigned short* accb = (unsigned short*)p; p += (size_t)3 * PP * 2;  // [3][NN][128]
    unsigned short* Wu   = (unsigned short*)p; p += (size_t)128 * 384 * 2;
    unsigned short* Wi   = (unsigned short*)p; p += (size_t)128 * 256 * 2;
    int* cnt    = (int*)p; p += (size_t)3 * NN * 4;
    int* cursor = (int*)p; p += (size_t)3 * NN * 4;
    int* rowst  = (int*)p; p += (size_t)3 * NN * 4;
    int* eidx   = (int*)p;                                   // [3*EE]

    float* out_user = (float*)d_out;
    float* out_item = out_user + PP;

    // rel 0: rated (tgt=user, src=item); rel 1: follows (u->u); rel 2: rates (tgt=item, src=user)
    hipMemsetAsync(cnt, 0, (size_t)6 * NN * sizeof(int), stream);
    cvtx_kernel<<<2048, 256, 0, stream>>>(x_user, x_item, xub, xib);
    wprep_kernel<<<128, 256, 0, stream>>>(w_rated_tgt, w_follows_tgt, w_rated_src,
                                          w_follows_src, w_rates_tgt, w_rates_src,
                                          Wu, Wi);
    const int EB3 = (3 * EE + 255) / 256;
    hist3_kernel<<<EB3, 256, 0, stream>>>(e_rated + EE, e_follows + EE, e_rates + EE, cnt);
    scan_kernel<<<1, 1024, 0, stream>>>(cnt, rowst, 3 * NN);
    place3_kernel<<<EB3, 256, 0, stream>>>(e_rated, e_rated + EE,
                                           e_follows, e_follows + EE,
                                           e_rates, e_rates + EE,
                                           rowst, cursor, eidx);
    gather3_kernel<<<(3 * NN * 64 + 255) / 256, 256, 0, stream>>>(
        xub, xib, rowst, cnt, eidx, accb);

    // out_user = relu(0.5*( x_user@(Wrt+Wft) + accR@Wrs + accF@Wfs ))
    dim3 gg((NN + 127) / 128, 2);
    mfma_gemm_kernel<<<gg, 256, 0, stream>>>(xub, accb, accb + PP, Wu,
                                             out_user, 0.5f, 6);
    // out_item = relu( x_item@Wit + accI@Wis )
    mfma_gemm_kernel<<<gg, 256, 0, stream>>>(xib, accb + 2 * PP, nullptr, Wi,
                                             out_item, 1.0f, 4);
}

// Round 5
// 416.104 us; speedup vs baseline: 2.4215x; 1.5536x over previous
//
#include <hip/hip_runtime.h>
#include <hip/hip_bf16.h>

constexpr int NN = 50000;      // nodes per type
constexpr int DD = 128;        // feature dim
constexpr int EE = 600000;     // edges per relation
constexpr long long PP = (long long)NN * DD;   // 6,400,000 elems per [N,128]

typedef __bf16 bf16x8 __attribute__((ext_vector_type(8)));
typedef float f32x4 __attribute__((ext_vector_type(4)));

__device__ inline unsigned short f2bs(float x) {
    __hip_bfloat16 b = __float2bfloat16(x);
    return *reinterpret_cast<unsigned short*>(&b);
}
__device__ inline float bs2f(unsigned short u) {
    union { float f; unsigned int u; } x; x.u = ((unsigned int)u) << 16; return x.f;
}

// f32 -> bf16 copies of x_user / x_item
__global__ void cvtx_kernel(const float* __restrict__ xu, const float* __restrict__ xi,
                            unsigned short* __restrict__ xub, unsigned short* __restrict__ xib) {
    const int total = (int)(PP / 4);
    for (int i = blockIdx.x * blockDim.x + threadIdx.x; i < total;
         i += gridDim.x * blockDim.x) {
        float4 a = ((const float4*)xu)[i];
        float4 b = ((const float4*)xi)[i];
        ushort4 oa, ob;
        oa.x = f2bs(a.x); oa.y = f2bs(a.y); oa.z = f2bs(a.z); oa.w = f2bs(a.w);
        ob.x = f2bs(b.x); ob.y = f2bs(b.y); ob.z = f2bs(b.z); ob.w = f2bs(b.w);
        ((ushort4*)xub)[i] = oa;
        ((ushort4*)xib)[i] = ob;
    }
}

// Transposed bf16 weights: Wu[n][384] = [Wrt+Wft ; Wrs ; Wfs]^T, Wi[n][256] = [Wit ; Wis]^T
__global__ void wprep_kernel(const float* __restrict__ wrt, const float* __restrict__ wft,
                             const float* __restrict__ wrs, const float* __restrict__ wfs,
                             const float* __restrict__ wit, const float* __restrict__ wis,
                             unsigned short* __restrict__ Wu, unsigned short* __restrict__ Wi) {
    int n = blockIdx.x;   // 0..127
    for (int k = threadIdx.x; k < 384; k += blockDim.x) {
        int seg = k >> 7, ks = k & 127;
        float v = (seg == 0) ? (wrt[ks * 128 + n] + wft[ks * 128 + n])
                : (seg == 1) ? wrs[ks * 128 + n] : wfs[ks * 128 + n];
        Wu[n * 384 + k] = f2bs(v);
    }
    for (int k = threadIdx.x; k < 256; k += blockDim.x) {
        int seg = k >> 7, ks = k & 127;
        float v = (seg == 0) ? wit[ks * 128 + n] : wis[ks * 128 + n];
        Wi[n * 256 + k] = f2bs(v);
    }
}

// histogram over all 3 relations (rel = idx/EE)
__global__ void hist3_kernel(const int* __restrict__ t0, const int* __restrict__ t1,
                             const int* __restrict__ t2, int* __restrict__ cnt) {
    int idx = blockIdx.x * blockDim.x + threadIdx.x;
    if (idx >= 3 * EE) return;
    int rel = idx / EE;
    int e = idx - rel * EE;
    const int* tp = (rel == 0) ? t0 : (rel == 1) ? t1 : t2;
    atomicAdd(&cnt[rel * NN + tp[e]], 1);
}

// ---- 3-stage hierarchical exclusive scan over n=150000 entries ----
// stage 1: per-block (4096 elems) local exclusive prefix + block total
__global__ __launch_bounds__(256) void scan_part_kernel(
    const int* __restrict__ cnt, int* __restrict__ rowst,
    int* __restrict__ bsum, int n) {
    const int tid = threadIdx.x;
    const int base = blockIdx.x * 4096 + tid * 16;
    int v[16];
    #pragma unroll
    for (int i = 0; i < 16; ++i) {
        int g = base + i;
        v[i] = (g < n) ? cnt[g] : 0;
    }
    int s = 0;
    #pragma unroll
    for (int i = 0; i < 16; ++i) s += v[i];
    const int lane = tid & 63, wv = tid >> 6;
    int incl = s;
    #pragma unroll
    for (int d = 1; d < 64; d <<= 1) {
        int u = __shfl_up(incl, d, 64);
        if (lane >= d) incl += u;
    }
    __shared__ int wsum[4];
    if (lane == 63) wsum[wv] = incl;
    __syncthreads();
    int woff = 0;
    for (int w = 0; w < wv; ++w) woff += wsum[w];
    int run = woff + incl - s;                 // exclusive prefix for this thread
    #pragma unroll
    for (int i = 0; i < 16; ++i) {
        int g = base + i;
        if (g < n) rowst[g] = run;
        run += v[i];
    }
    if (tid == 255) bsum[blockIdx.x] = woff + incl;   // block total
}

// stage 2: tiny serial scan of block totals (nb ~ 37)
__global__ void scan_tops_kernel(int* __restrict__ bsum, int nb) {
    if (threadIdx.x == 0 && blockIdx.x == 0) {
        int run = 0;
        for (int i = 0; i < nb; ++i) { int v = bsum[i]; bsum[i] = run; run += v; }
    }
}

// stage 3: add block offsets
__global__ void scan_add_kernel(int* __restrict__ rowst, const int* __restrict__ bsum,
                                int n) {
    int i = blockIdx.x * blockDim.x + threadIdx.x;
    if (i < n) rowst[i] += bsum[i >> 12];
}

__global__ void place3_kernel(const int* __restrict__ s0, const int* __restrict__ t0,
                              const int* __restrict__ s1, const int* __restrict__ t1,
                              const int* __restrict__ s2, const int* __restrict__ t2,
                              const int* __restrict__ rowst, int* __restrict__ cursor,
                              int* __restrict__ eidx) {
    int idx = blockIdx.x * blockDim.x + threadIdx.x;
    if (idx >= 3 * EE) return;
    int rel = idx / EE;
    int e = idx - rel * EE;
    const int* tp = (rel == 0) ? t0 : (rel == 1) ? t1 : t2;
    const int* sp = (rel == 0) ? s0 : (rel == 1) ? s1 : s2;
    int t = rel * NN + tp[e];
    int pos = atomicAdd(&cursor[t], 1);
    eidx[rowst[t] + pos] = sp[e];
}

// one wave per (rel,row): mean of bf16 src rows -> bf16 acc row
__global__ __launch_bounds__(256) void gather3_kernel(
    const unsigned short* __restrict__ xub, const unsigned short* __restrict__ xib,
    const int* __restrict__ rowst, const int* __restrict__ cnt,
    const int* __restrict__ eidx, unsigned short* __restrict__ accb) {
    int rr = (int)((blockIdx.x * blockDim.x + threadIdx.x) >> 6);
    int lane = threadIdx.x & 63;
    if (rr >= 3 * NN) return;
    int rel = rr / NN;                      // 0: rated(src=item) 1: follows 2: rates
    const unsigned short* src = (rel == 0) ? xib : xub;
    int start = rowst[rr], deg = cnt[rr];
    float s0 = 0.f, s1 = 0.f;
    for (int j = 0; j < deg; ++j) {
        int sr = eidx[start + j];
        unsigned int v = *(const unsigned int*)(src + (size_t)sr * DD + lane * 2);
        s0 += bs2f((unsigned short)(v & 0xffff));
        s1 += bs2f((unsigned short)(v >> 16));
    }
    float inv = 1.0f / (float)(deg > 1 ? deg : 1);
    unsigned int o = ((unsigned int)f2bs(s1 * inv) << 16) | f2bs(s0 * inv);
    *(unsigned int*)(accb + (size_t)rr * DD + lane * 2) = o;
}

// C[50000,128] = relu(postmul * concat_K(segs) @ Wt^T), bf16 MFMA, f32 out.
// A segs: up to 3 bf16 [NN][128] matrices, K = ksteps*64 (128 per segment).
// Wt: bf16 [128 n][Ktot k]. Tile: BM=128, BN=64, BK=64, 4 waves.
__global__ __launch_bounds__(256) void mfma_gemm_kernel(
    const unsigned short* __restrict__ a0, const unsigned short* __restrict__ a1,
    const unsigned short* __restrict__ a2, const unsigned short* __restrict__ Wt,
    float* __restrict__ outp, float postmul, int ksteps) {
    __shared__ unsigned char lAb[128 * 128];   // [128 rows][64 k] bf16, XOR-swizzled
    __shared__ unsigned char lBb[64 * 128];    // [64 n][64 k] bf16, XOR-swizzled

    const int tid = threadIdx.x;
    const int m0 = blockIdx.x * 128;
    const int n0 = blockIdx.y * 64;
    const int Ktot = ksteps * 64;
    const int wv = tid >> 6, lane = tid & 63;

    f32x4 acc[2][4];
    #pragma unroll
    for (int i = 0; i < 2; ++i)
        #pragma unroll
        for (int j = 0; j < 4; ++j) acc[i][j] = (f32x4)(0.f);

    for (int kt = 0; kt < ksteps; ++kt) {
        const unsigned short* As = (kt >> 1) == 0 ? a0 : (kt >> 1) == 1 ? a1 : a2;
        const int ks0 = (kt & 1) * 64;
        // stage A: 128x64 bf16 = 2048 x 8B units, 8 per thread
        #pragma unroll
        for (int i = 0; i < 8; ++i) {
            int idx = i * 256 + tid;
            int row = idx >> 4, ku = idx & 15;     // 16 units/row
            int g = m0 + row;
            unsigned long long v = 0ull;
            if (g < NN)
                v = *(const unsigned long long*)(As + (size_t)g * DD + ks0 + ku * 4);
            int byte = (row * 128 + ku * 8) ^ ((row & 7) << 4);
            *(unsigned long long*)(lAb + byte) = v;
        }
        // stage B: 64x64 bf16 = 1024 x 8B units, 4 per thread
        #pragma unroll
        for (int i = 0; i < 4; ++i) {
            int idx = i * 256 + tid;
            int n = idx >> 4, ku = idx & 15;
            unsigned long long v =
                *(const unsigned long long*)(Wt + (size_t)(n0 + n) * Ktot + kt * 64 + ku * 4);
            int byte = (n * 128 + ku * 8) ^ ((n & 7) << 4);
            *(unsigned long long*)(lBb + byte) = v;
        }
        __syncthreads();

        #pragma unroll
        for (int kk = 0; kk < 2; ++kk) {           // k-half within BK=64
            bf16x8 af[2], bfr[4];
            #pragma unroll
            for (int mi = 0; mi < 2; ++mi) {
                int row = wv * 32 + mi * 16 + (lane & 15);
                int byte = (row * 128 + kk * 64 + (lane >> 4) * 16) ^ ((row & 7) << 4);
                af[mi] = *(const bf16x8*)(lAb + byte);
            }
            #pragma unroll
            for (int ni = 0; ni < 4; ++ni) {
                int n = ni * 16 + (lane & 15);
                int byte = (n * 128 + kk * 64 + (lane >> 4) * 16) ^ ((n & 7) << 4);
                bfr[ni] = *(const bf16x8*)(lBb + byte);
            }
            #pragma unroll
            for (int mi = 0; mi < 2; ++mi)
                #pragma unroll
                for (int ni = 0; ni < 4; ++ni)
                    acc[mi][ni] = __builtin_amdgcn_mfma_f32_16x16x32_bf16(
                        af[mi], bfr[ni], acc[mi][ni], 0, 0, 0);
        }
        __syncthreads();
    }

    // epilogue: C frag mapping col=lane&15, row=(lane>>4)*4+r  [m89/m91]
    #pragma unroll
    for (int mi = 0; mi < 2; ++mi) {
        #pragma unroll
        for (int ni = 0; ni < 4; ++ni) {
            #pragma unroll
            for (int r = 0; r < 4; ++r) {
                int g = m0 + wv * 32 + mi * 16 + (lane >> 4) * 4 + r;
                if (g < NN) {
                    float v = acc[mi][ni][r] * postmul;
                    outp[(size_t)g * DD + n0 + ni * 16 + (lane & 15)] = v > 0.f ? v : 0.f;
                }
            }
        }
    }
}

extern "C" void kernel_launch(void* const* d_in, const int* in_sizes, int n_in,
                              void* d_out, int out_size, void* d_ws, size_t ws_size,
                              hipStream_t stream) {
    const float* x_user = (const float*)d_in[0];
    const float* x_item = (const float*)d_in[1];
    const float* w_rates_src   = (const float*)d_in[2];
    const float* w_rates_tgt   = (const float*)d_in[3];
    const float* w_rated_src   = (const float*)d_in[4];
    const float* w_rated_tgt   = (const float*)d_in[5];
    const float* w_follows_src = (const float*)d_in[6];
    const float* w_follows_tgt = (const float*)d_in[7];
    const int* e_rates   = (const int*)d_in[8];    // row0 src(user), row1 tgt(item)
    const int* e_rated   = (const int*)d_in[9];    // row0 src(item), row1 tgt(user)
    const int* e_follows = (const int*)d_in[10];   // row0 src(user), row1 tgt(user)

    // ---- workspace carve-up (~73 MB) ----
    char* p = (char*)d_ws;
    unsigned short* xub  = (unsigned short*)p; p += (size_t)PP * 2;
    unsigned short* xib  = (unsigned short*)p; p += (size_t)PP * 2;
    unsigned short* accb = (unsigned short*)p; p += (size_t)3 * PP * 2;  // [3][NN][128]
    unsigned short* Wu   = (unsigned short*)p; p += (size_t)128 * 384 * 2;
    unsigned short* Wi   = (unsigned short*)p; p += (size_t)128 * 256 * 2;
    int* cnt    = (int*)p; p += (size_t)3 * NN * 4;
    int* cursor = (int*)p; p += (size_t)3 * NN * 4;
    int* rowst  = (int*)p; p += (size_t)3 * NN * 4;
    int* bsum   = (int*)p; p += (size_t)64 * 4;
    int* eidx   = (int*)p;                                   // [3*EE]

    float* out_user = (float*)d_out;
    float* out_item = out_user + PP;

    const int NSCAN = 3 * NN;                 // 150000
    const int NB = (NSCAN + 4095) / 4096;     // 37 scan blocks

    // rel 0: rated (tgt=user, src=item); rel 1: follows (u->u); rel 2: rates (tgt=item, src=user)
    hipMemsetAsync(cnt, 0, (size_t)6 * NN * sizeof(int), stream);
    cvtx_kernel<<<2048, 256, 0, stream>>>(x_user, x_item, xub, xib);
    wprep_kernel<<<128, 256, 0, stream>>>(w_rated_tgt, w_follows_tgt, w_rated_src,
                                          w_follows_src, w_rates_tgt, w_rates_src,
                                          Wu, Wi);
    const int EB3 = (3 * EE + 255) / 256;
    hist3_kernel<<<EB3, 256, 0, stream>>>(e_rated + EE, e_follows + EE, e_rates + EE, cnt);
    scan_part_kernel<<<NB, 256, 0, stream>>>(cnt, rowst, bsum, NSCAN);
    scan_tops_kernel<<<1, 64, 0, stream>>>(bsum, NB);
    scan_add_kernel<<<(NSCAN + 255) / 256, 256, 0, stream>>>(rowst, bsum, NSCAN);
    place3_kernel<<<EB3, 256, 0, stream>>>(e_rated, e_rated + EE,
                                           e_follows, e_follows + EE,
                                           e_rates, e_rates + EE,
                                           rowst, cursor, eidx);
    gather3_kernel<<<(3 * NN * 64 + 255) / 256, 256, 0, stream>>>(
        xub, xib, rowst, cnt, eidx, accb);

    // out_user = relu(0.5*( x_user@(Wrt+Wft) + accR@Wrs + accF@Wfs ))
    dim3 gg((NN + 127) / 128, 2);
    mfma_gemm_kernel<<<gg, 256, 0, stream>>>(xub, accb, accb + PP, Wu,
                                             out_user, 0.5f, 6);
    // out_item = relu( x_item@Wit + accI@Wis )
    mfma_gemm_kernel<<<gg, 256, 0, stream>>>(xib, accb + 2 * PP, nullptr, Wi,
                                             out_item, 1.0f, 4);
}

// Round 6
// 306.574 us; speedup vs baseline: 3.2866x; 1.3573x over previous
//
#include <hip/hip_runtime.h>
#include <hip/hip_bf16.h>

constexpr int NN = 50000;      // nodes per type
constexpr int DD = 128;        // feature dim
constexpr int EE = 600000;     // edges per relation
constexpr long long PP = (long long)NN * DD;   // 6,400,000 elems per [N,128]

typedef __bf16 bf16x8 __attribute__((ext_vector_type(8)));
typedef float f32x4 __attribute__((ext_vector_type(4)));

__device__ inline unsigned short f2bs(float x) {
    __hip_bfloat16 b = __float2bfloat16(x);
    return *reinterpret_cast<unsigned short*>(&b);
}
__device__ inline float bs2f(unsigned short u) {
    union { float f; unsigned int u; } x; x.u = ((unsigned int)u) << 16; return x.f;
}

// f32 -> bf16 copies of x_user / x_item
__global__ void cvtx_kernel(const float* __restrict__ xu, const float* __restrict__ xi,
                            unsigned short* __restrict__ xub, unsigned short* __restrict__ xib) {
    const int total = (int)(PP / 4);
    for (int i = blockIdx.x * blockDim.x + threadIdx.x; i < total;
         i += gridDim.x * blockDim.x) {
        float4 a = ((const float4*)xu)[i];
        float4 b = ((const float4*)xi)[i];
        ushort4 oa, ob;
        oa.x = f2bs(a.x); oa.y = f2bs(a.y); oa.z = f2bs(a.z); oa.w = f2bs(a.w);
        ob.x = f2bs(b.x); ob.y = f2bs(b.y); ob.z = f2bs(b.z); ob.w = f2bs(b.w);
        ((ushort4*)xub)[i] = oa;
        ((ushort4*)xib)[i] = ob;
    }
}

// Transposed bf16 weights: Wu[n][384] = [Wrt+Wft ; Wrs ; Wfs]^T, Wi[n][256] = [Wit ; Wis]^T
__global__ void wprep_kernel(const float* __restrict__ wrt, const float* __restrict__ wft,
                             const float* __restrict__ wrs, const float* __restrict__ wfs,
                             const float* __restrict__ wit, const float* __restrict__ wis,
                             unsigned short* __restrict__ Wu, unsigned short* __restrict__ Wi) {
    int n = blockIdx.x;   // 0..127
    for (int k = threadIdx.x; k < 384; k += blockDim.x) {
        int seg = k >> 7, ks = k & 127;
        float v = (seg == 0) ? (wrt[ks * 128 + n] + wft[ks * 128 + n])
                : (seg == 1) ? wrs[ks * 128 + n] : wfs[ks * 128 + n];
        Wu[n * 384 + k] = f2bs(v);
    }
    for (int k = threadIdx.x; k < 256; k += blockDim.x) {
        int seg = k >> 7, ks = k & 127;
        float v = (seg == 0) ? wit[ks * 128 + n] : wis[ks * 128 + n];
        Wi[n * 256 + k] = f2bs(v);
    }
}

// histogram over all 3 relations (rel = idx/EE)
__global__ void hist3_kernel(const int* __restrict__ t0, const int* __restrict__ t1,
                             const int* __restrict__ t2, int* __restrict__ cnt) {
    int idx = blockIdx.x * blockDim.x + threadIdx.x;
    if (idx >= 3 * EE) return;
    int rel = idx / EE;
    int e = idx - rel * EE;
    const int* tp = (rel == 0) ? t0 : (rel == 1) ? t1 : t2;
    atomicAdd(&cnt[rel * NN + tp[e]], 1);
}

// ---- 3-stage hierarchical exclusive scan over n=150000 entries ----
__global__ __launch_bounds__(256) void scan_part_kernel(
    const int* __restrict__ cnt, int* __restrict__ rowst,
    int* __restrict__ bsum, int n) {
    const int tid = threadIdx.x;
    const int base = blockIdx.x * 4096 + tid * 16;
    int v[16];
    #pragma unroll
    for (int i = 0; i < 16; ++i) {
        int g = base + i;
        v[i] = (g < n) ? cnt[g] : 0;
    }
    int s = 0;
    #pragma unroll
    for (int i = 0; i < 16; ++i) s += v[i];
    const int lane = tid & 63, wv = tid >> 6;
    int incl = s;
    #pragma unroll
    for (int d = 1; d < 64; d <<= 1) {
        int u = __shfl_up(incl, d, 64);
        if (lane >= d) incl += u;
    }
    __shared__ int wsum[4];
    if (lane == 63) wsum[wv] = incl;
    __syncthreads();
    int woff = 0;
    for (int w = 0; w < wv; ++w) woff += wsum[w];
    int run = woff + incl - s;                 // exclusive prefix for this thread
    #pragma unroll
    for (int i = 0; i < 16; ++i) {
        int g = base + i;
        if (g < n) rowst[g] = run;
        run += v[i];
    }
    if (tid == 255) bsum[blockIdx.x] = woff + incl;   // block total
}

__global__ void scan_tops_kernel(int* __restrict__ bsum, int nb) {
    if (threadIdx.x == 0 && blockIdx.x == 0) {
        int run = 0;
        for (int i = 0; i < nb; ++i) { int v = bsum[i]; bsum[i] = run; run += v; }
    }
}

__global__ void scan_add_kernel(int* __restrict__ rowst, const int* __restrict__ bsum,
                                int n) {
    int i = blockIdx.x * blockDim.x + threadIdx.x;
    if (i < n) rowst[i] += bsum[i >> 12];
}

__global__ void place3_kernel(const int* __restrict__ s0, const int* __restrict__ t0,
                              const int* __restrict__ s1, const int* __restrict__ t1,
                              const int* __restrict__ s2, const int* __restrict__ t2,
                              const int* __restrict__ rowst, int* __restrict__ cursor,
                              int* __restrict__ eidx) {
    int idx = blockIdx.x * blockDim.x + threadIdx.x;
    if (idx >= 3 * EE) return;
    int rel = idx / EE;
    int e = idx - rel * EE;
    const int* tp = (rel == 0) ? t0 : (rel == 1) ? t1 : t2;
    const int* sp = (rel == 0) ? s0 : (rel == 1) ? s1 : s2;
    int t = rel * NN + tp[e];
    int pos = atomicAdd(&cursor[t], 1);
    eidx[rowst[t] + pos] = sp[e];
}

// 16 lanes per target row (4 rows per wave), 16B/lane loads, degree loop
// unrolled x2 -> up to 8 outstanding 256B row-reads per wave (MLP).
__global__ __launch_bounds__(256) void gather3_kernel(
    const unsigned short* __restrict__ xub, const unsigned short* __restrict__ xib,
    const int* __restrict__ rowst, const int* __restrict__ cnt,
    const int* __restrict__ eidx, unsigned short* __restrict__ accb) {
    int rr = (int)((blockIdx.x * blockDim.x + threadIdx.x) >> 4);
    int l = threadIdx.x & 15;               // lane within 16-lane row group
    if (rr >= 3 * NN) return;
    int rel = rr / NN;                      // 0: rated(src=item) 1: follows 2: rates
    const unsigned short* src = (rel == 0) ? xib : xub;
    int start = rowst[rr], deg = cnt[rr];
    float s0 = 0.f, s1 = 0.f, s2 = 0.f, s3 = 0.f,
          s4 = 0.f, s5 = 0.f, s6 = 0.f, s7 = 0.f;
    int j = 0;
    for (; j + 2 <= deg; j += 2) {
        int sra = eidx[start + j];
        int srb = eidx[start + j + 1];
        uint4 va = *(const uint4*)(src + (size_t)sra * DD + l * 8);
        uint4 vb = *(const uint4*)(src + (size_t)srb * DD + l * 8);
        s0 += bs2f((unsigned short)(va.x & 0xffff)) + bs2f((unsigned short)(vb.x & 0xffff));
        s1 += bs2f((unsigned short)(va.x >> 16))    + bs2f((unsigned short)(vb.x >> 16));
        s2 += bs2f((unsigned short)(va.y & 0xffff)) + bs2f((unsigned short)(vb.y & 0xffff));
        s3 += bs2f((unsigned short)(va.y >> 16))    + bs2f((unsigned short)(vb.y >> 16));
        s4 += bs2f((unsigned short)(va.z & 0xffff)) + bs2f((unsigned short)(vb.z & 0xffff));
        s5 += bs2f((unsigned short)(va.z >> 16))    + bs2f((unsigned short)(vb.z >> 16));
        s6 += bs2f((unsigned short)(va.w & 0xffff)) + bs2f((unsigned short)(vb.w & 0xffff));
        s7 += bs2f((unsigned short)(va.w >> 16))    + bs2f((unsigned short)(vb.w >> 16));
    }
    if (j < deg) {
        int sra = eidx[start + j];
        uint4 va = *(const uint4*)(src + (size_t)sra * DD + l * 8);
        s0 += bs2f((unsigned short)(va.x & 0xffff));
        s1 += bs2f((unsigned short)(va.x >> 16));
        s2 += bs2f((unsigned short)(va.y & 0xffff));
        s3 += bs2f((unsigned short)(va.y >> 16));
        s4 += bs2f((unsigned short)(va.z & 0xffff));
        s5 += bs2f((unsigned short)(va.z >> 16));
        s6 += bs2f((unsigned short)(va.w & 0xffff));
        s7 += bs2f((unsigned short)(va.w >> 16));
    }
    float inv = 1.0f / (float)(deg > 1 ? deg : 1);
    uint4 o;
    o.x = ((unsigned int)f2bs(s1 * inv) << 16) | f2bs(s0 * inv);
    o.y = ((unsigned int)f2bs(s3 * inv) << 16) | f2bs(s2 * inv);
    o.z = ((unsigned int)f2bs(s5 * inv) << 16) | f2bs(s4 * inv);
    o.w = ((unsigned int)f2bs(s7 * inv) << 16) | f2bs(s6 * inv);
    *(uint4*)(accb + (size_t)rr * DD + l * 8) = o;
}

// C[50000,128] = relu(postmul * concat_K(segs) @ Wt^T), bf16 MFMA, f32 out.
// A segs: up to 3 bf16 [NN][128] matrices, K = ksteps*64 (128 per segment).
// Wt: bf16 [128 n][Ktot k]. Tile: BM=128, BN=64, BK=64, 4 waves.
__global__ __launch_bounds__(256) void mfma_gemm_kernel(
    const unsigned short* __restrict__ a0, const unsigned short* __restrict__ a1,
    const unsigned short* __restrict__ a2, const unsigned short* __restrict__ Wt,
    float* __restrict__ outp, float postmul, int ksteps) {
    __shared__ unsigned char lAb[128 * 128];   // [128 rows][64 k] bf16, XOR-swizzled
    __shared__ unsigned char lBb[64 * 128];    // [64 n][64 k] bf16, XOR-swizzled

    const int tid = threadIdx.x;
    const int m0 = blockIdx.x * 128;
    const int n0 = blockIdx.y * 64;
    const int Ktot = ksteps * 64;
    const int wv = tid >> 6, lane = tid & 63;

    f32x4 acc[2][4];
    #pragma unroll
    for (int i = 0; i < 2; ++i)
        #pragma unroll
        for (int j = 0; j < 4; ++j) acc[i][j] = (f32x4)(0.f);

    for (int kt = 0; kt < ksteps; ++kt) {
        const unsigned short* As = (kt >> 1) == 0 ? a0 : (kt >> 1) == 1 ? a1 : a2;
        const int ks0 = (kt & 1) * 64;
        // stage A: 128x64 bf16 = 2048 x 8B units, 8 per thread
        #pragma unroll
        for (int i = 0; i < 8; ++i) {
            int idx = i * 256 + tid;
            int row = idx >> 4, ku = idx & 15;     // 16 units/row
            int g = m0 + row;
            unsigned long long v = 0ull;
            if (g < NN)
                v = *(const unsigned long long*)(As + (size_t)g * DD + ks0 + ku * 4);
            int byte = (row * 128 + ku * 8) ^ ((row & 7) << 4);
            *(unsigned long long*)(lAb + byte) = v;
        }
        // stage B: 64x64 bf16 = 1024 x 8B units, 4 per thread
        #pragma unroll
        for (int i = 0; i < 4; ++i) {
            int idx = i * 256 + tid;
            int n = idx >> 4, ku = idx & 15;
            unsigned long long v =
                *(const unsigned long long*)(Wt + (size_t)(n0 + n) * Ktot + kt * 64 + ku * 4);
            int byte = (n * 128 + ku * 8) ^ ((n & 7) << 4);
            *(unsigned long long*)(lBb + byte) = v;
        }
        __syncthreads();

        #pragma unroll
        for (int kk = 0; kk < 2; ++kk) {           // k-half within BK=64
            bf16x8 af[2], bfr[4];
            #pragma unroll
            for (int mi = 0; mi < 2; ++mi) {
                int row = wv * 32 + mi * 16 + (lane & 15);
                int byte = (row * 128 + kk * 64 + (lane >> 4) * 16) ^ ((row & 7) << 4);
                af[mi] = *(const bf16x8*)(lAb + byte);
            }
            #pragma unroll
            for (int ni = 0; ni < 4; ++ni) {
                int n = ni * 16 + (lane & 15);
                int byte = (n * 128 + kk * 64 + (lane >> 4) * 16) ^ ((n & 7) << 4);
                bfr[ni] = *(const bf16x8*)(lBb + byte);
            }
            #pragma unroll
            for (int mi = 0; mi < 2; ++mi)
                #pragma unroll
                for (int ni = 0; ni < 4; ++ni)
                    acc[mi][ni] = __builtin_amdgcn_mfma_f32_16x16x32_bf16(
                        af[mi], bfr[ni], acc[mi][ni], 0, 0, 0);
        }
        __syncthreads();
    }

    // epilogue: C frag mapping col=lane&15, row=(lane>>4)*4+r  [m89/m91]
    #pragma unroll
    for (int mi = 0; mi < 2; ++mi) {
        #pragma unroll
        for (int ni = 0; ni < 4; ++ni) {
            #pragma unroll
            for (int r = 0; r < 4; ++r) {
                int g = m0 + wv * 32 + mi * 16 + (lane >> 4) * 4 + r;
                if (g < NN) {
                    float v = acc[mi][ni][r] * postmul;
                    outp[(size_t)g * DD + n0 + ni * 16 + (lane & 15)] = v > 0.f ? v : 0.f;
                }
            }
        }
    }
}

extern "C" void kernel_launch(void* const* d_in, const int* in_sizes, int n_in,
                              void* d_out, int out_size, void* d_ws, size_t ws_size,
                              hipStream_t stream) {
    const float* x_user = (const float*)d_in[0];
    const float* x_item = (const float*)d_in[1];
    const float* w_rates_src   = (const float*)d_in[2];
    const float* w_rates_tgt   = (const float*)d_in[3];
    const float* w_rated_src   = (const float*)d_in[4];
    const float* w_rated_tgt   = (const float*)d_in[5];
    const float* w_follows_src = (const float*)d_in[6];
    const float* w_follows_tgt = (const float*)d_in[7];
    const int* e_rates   = (const int*)d_in[8];    // row0 src(user), row1 tgt(item)
    const int* e_rated   = (const int*)d_in[9];    // row0 src(item), row1 tgt(user)
    const int* e_follows = (const int*)d_in[10];   // row0 src(user), row1 tgt(user)

    // ---- workspace carve-up (~73 MB) ----
    char* p = (char*)d_ws;
    unsigned short* xub  = (unsigned short*)p; p += (size_t)PP * 2;
    unsigned short* xib  = (unsigned short*)p; p += (size_t)PP * 2;
    unsigned short* accb = (unsigned short*)p; p += (size_t)3 * PP * 2;  // [3][NN][128]
    unsigned short* Wu   = (unsigned short*)p; p += (size_t)128 * 384 * 2;
    unsigned short* Wi   = (unsigned short*)p; p += (size_t)128 * 256 * 2;
    int* cnt    = (int*)p; p += (size_t)3 * NN * 4;
    int* cursor = (int*)p; p += (size_t)3 * NN * 4;
    int* rowst  = (int*)p; p += (size_t)3 * NN * 4;
    int* bsum   = (int*)p; p += (size_t)64 * 4;
    int* eidx   = (int*)p;                                   // [3*EE]

    float* out_user = (float*)d_out;
    float* out_item = out_user + PP;

    const int NSCAN = 3 * NN;                 // 150000
    const int NB = (NSCAN + 4095) / 4096;     // 37 scan blocks

    // rel 0: rated (tgt=user, src=item); rel 1: follows (u->u); rel 2: rates (tgt=item, src=user)
    hipMemsetAsync(cnt, 0, (size_t)6 * NN * sizeof(int), stream);
    cvtx_kernel<<<2048, 256, 0, stream>>>(x_user, x_item, xub, xib);
    wprep_kernel<<<128, 256, 0, stream>>>(w_rated_tgt, w_follows_tgt, w_rated_src,
                                          w_follows_src, w_rates_tgt, w_rates_src,
                                          Wu, Wi);
    const int EB3 = (3 * EE + 255) / 256;
    hist3_kernel<<<EB3, 256, 0, stream>>>(e_rated + EE, e_follows + EE, e_rates + EE, cnt);
    scan_part_kernel<<<NB, 256, 0, stream>>>(cnt, rowst, bsum, NSCAN);
    scan_tops_kernel<<<1, 64, 0, stream>>>(bsum, NB);
    scan_add_kernel<<<(NSCAN + 255) / 256, 256, 0, stream>>>(rowst, bsum, NSCAN);
    place3_kernel<<<EB3, 256, 0, stream>>>(e_rated, e_rated + EE,
                                           e_follows, e_follows + EE,
                                           e_rates, e_rates + EE,
                                           rowst, cursor, eidx);
    gather3_kernel<<<(3 * NN * 16 + 255) / 256, 256, 0, stream>>>(
        xub, xib, rowst, cnt, eidx, accb);

    // out_user = relu(0.5*( x_user@(Wrt+Wft) + accR@Wrs + accF@Wfs ))
    dim3 gg((NN + 127) / 128, 2);
    mfma_gemm_kernel<<<gg, 256, 0, stream>>>(xub, accb, accb + PP, Wu,
                                             out_user, 0.5f, 6);
    // out_item = relu( x_item@Wit + accI@Wis )
    mfma_gemm_kernel<<<gg, 256, 0, stream>>>(xib, accb + 2 * PP, nullptr, Wi,
                                             out_item, 1.0f, 4);
}

// Round 7
// 290.303 us; speedup vs baseline: 3.4708x; 1.0560x over previous
//
#include <hip/hip_runtime.h>
#include <hip/hip_bf16.h>

constexpr int NN = 50000;      // nodes per type
constexpr int DD = 128;        // feature dim
constexpr int EE = 600000;     // edges per relation
constexpr long long PP = (long long)NN * DD;   // 6,400,000 elems per [N,128]

typedef __bf16 bf16x8 __attribute__((ext_vector_type(8)));
typedef float f32x4 __attribute__((ext_vector_type(4)));

__device__ inline unsigned short f2bs(float x) {
    __hip_bfloat16 b = __float2bfloat16(x);
    return *reinterpret_cast<unsigned short*>(&b);
}
__device__ inline float bs2f(unsigned short u) {
    union { float f; unsigned int u; } x; x.u = ((unsigned int)u) << 16; return x.f;
}

// f32 -> bf16 copies of x_user / x_item
__global__ void cvtx_kernel(const float* __restrict__ xu, const float* __restrict__ xi,
                            unsigned short* __restrict__ xub, unsigned short* __restrict__ xib) {
    const int total = (int)(PP / 4);
    for (int i = blockIdx.x * blockDim.x + threadIdx.x; i < total;
         i += gridDim.x * blockDim.x) {
        float4 a = ((const float4*)xu)[i];
        float4 b = ((const float4*)xi)[i];
        ushort4 oa, ob;
        oa.x = f2bs(a.x); oa.y = f2bs(a.y); oa.z = f2bs(a.z); oa.w = f2bs(a.w);
        ob.x = f2bs(b.x); ob.y = f2bs(b.y); ob.z = f2bs(b.z); ob.w = f2bs(b.w);
        ((ushort4*)xub)[i] = oa;
        ((ushort4*)xib)[i] = ob;
    }
}

// Transposed bf16 weights: Wu[n][384] = [Wrt+Wft ; Wrs ; Wfs]^T, Wi[n][256] = [Wit ; Wis]^T
__global__ void wprep_kernel(const float* __restrict__ wrt, const float* __restrict__ wft,
                             const float* __restrict__ wrs, const float* __restrict__ wfs,
                             const float* __restrict__ wit, const float* __restrict__ wis,
                             unsigned short* __restrict__ Wu, unsigned short* __restrict__ Wi) {
    int n = blockIdx.x;   // 0..127
    for (int k = threadIdx.x; k < 384; k += blockDim.x) {
        int seg = k >> 7, ks = k & 127;
        float v = (seg == 0) ? (wrt[ks * 128 + n] + wft[ks * 128 + n])
                : (seg == 1) ? wrs[ks * 128 + n] : wfs[ks * 128 + n];
        Wu[n * 384 + k] = f2bs(v);
    }
    for (int k = threadIdx.x; k < 256; k += blockDim.x) {
        int seg = k >> 7, ks = k & 127;
        float v = (seg == 0) ? wit[ks * 128 + n] : wis[ks * 128 + n];
        Wi[n * 256 + k] = f2bs(v);
    }
}

// histogram over all 3 relations (rel = idx/EE)
__global__ void hist3_kernel(const int* __restrict__ t0, const int* __restrict__ t1,
                             const int* __restrict__ t2, int* __restrict__ cnt) {
    int idx = blockIdx.x * blockDim.x + threadIdx.x;
    if (idx >= 3 * EE) return;
    int rel = idx / EE;
    int e = idx - rel * EE;
    const int* tp = (rel == 0) ? t0 : (rel == 1) ? t1 : t2;
    atomicAdd(&cnt[rel * NN + tp[e]], 1);
}

// ---- 3-stage hierarchical exclusive scan over n=150000 entries ----
__global__ __launch_bounds__(256) void scan_part_kernel(
    const int* __restrict__ cnt, int* __restrict__ rowst,
    int* __restrict__ bsum, int n) {
    const int tid = threadIdx.x;
    const int base = blockIdx.x * 4096 + tid * 16;
    int v[16];
    #pragma unroll
    for (int i = 0; i < 16; ++i) {
        int g = base + i;
        v[i] = (g < n) ? cnt[g] : 0;
    }
    int s = 0;
    #pragma unroll
    for (int i = 0; i < 16; ++i) s += v[i];
    const int lane = tid & 63, wv = tid >> 6;
    int incl = s;
    #pragma unroll
    for (int d = 1; d < 64; d <<= 1) {
        int u = __shfl_up(incl, d, 64);
        if (lane >= d) incl += u;
    }
    __shared__ int wsum[4];
    if (lane == 63) wsum[wv] = incl;
    __syncthreads();
    int woff = 0;
    for (int w = 0; w < wv; ++w) woff += wsum[w];
    int run = woff + incl - s;                 // exclusive prefix for this thread
    #pragma unroll
    for (int i = 0; i < 16; ++i) {
        int g = base + i;
        if (g < n) rowst[g] = run;
        run += v[i];
    }
    if (tid == 255) bsum[blockIdx.x] = woff + incl;   // block total
}

__global__ void scan_tops_kernel(int* __restrict__ bsum, int nb) {
    if (threadIdx.x == 0 && blockIdx.x == 0) {
        int run = 0;
        for (int i = 0; i < nb; ++i) { int v = bsum[i]; bsum[i] = run; run += v; }
    }
}

__global__ void scan_add_kernel(int* __restrict__ rowst, const int* __restrict__ bsum,
                                int n) {
    int i = blockIdx.x * blockDim.x + threadIdx.x;
    if (i < n) rowst[i] += bsum[i >> 12];
}

// u16 eidx: halves scatter footprint to 3.6MB (L2-resident) -> kills the
// 64B-line write amplification that made this the top dispatch (119MB WRITE).
__global__ void place3_kernel(const int* __restrict__ s0, const int* __restrict__ t0,
                              const int* __restrict__ s1, const int* __restrict__ t1,
                              const int* __restrict__ s2, const int* __restrict__ t2,
                              const int* __restrict__ rowst, int* __restrict__ cursor,
                              unsigned short* __restrict__ eidx) {
    int idx = blockIdx.x * blockDim.x + threadIdx.x;
    if (idx >= 3 * EE) return;
    int rel = idx / EE;
    int e = idx - rel * EE;
    const int* tp = (rel == 0) ? t0 : (rel == 1) ? t1 : t2;
    const int* sp = (rel == 0) ? s0 : (rel == 1) ? s1 : s2;
    int t = rel * NN + tp[e];
    int pos = atomicAdd(&cursor[t], 1);
    eidx[rowst[t] + pos] = (unsigned short)sp[e];
}

// 16 lanes per target row (4 rows per wave), 16B/lane loads, degree loop
// unrolled x2 -> up to 8 outstanding 256B row-reads per wave (MLP).
__global__ __launch_bounds__(256) void gather3_kernel(
    const unsigned short* __restrict__ xub, const unsigned short* __restrict__ xib,
    const int* __restrict__ rowst, const int* __restrict__ cnt,
    const unsigned short* __restrict__ eidx, unsigned short* __restrict__ accb) {
    int rr = (int)((blockIdx.x * blockDim.x + threadIdx.x) >> 4);
    int l = threadIdx.x & 15;               // lane within 16-lane row group
    if (rr >= 3 * NN) return;
    int rel = rr / NN;                      // 0: rated(src=item) 1: follows 2: rates
    const unsigned short* src = (rel == 0) ? xib : xub;
    int start = rowst[rr], deg = cnt[rr];
    float s0 = 0.f, s1 = 0.f, s2 = 0.f, s3 = 0.f,
          s4 = 0.f, s5 = 0.f, s6 = 0.f, s7 = 0.f;
    int j = 0;
    for (; j + 2 <= deg; j += 2) {
        int sra = eidx[start + j];
        int srb = eidx[start + j + 1];
        uint4 va = *(const uint4*)(src + (size_t)sra * DD + l * 8);
        uint4 vb = *(const uint4*)(src + (size_t)srb * DD + l * 8);
        s0 += bs2f((unsigned short)(va.x & 0xffff)) + bs2f((unsigned short)(vb.x & 0xffff));
        s1 += bs2f((unsigned short)(va.x >> 16))    + bs2f((unsigned short)(vb.x >> 16));
        s2 += bs2f((unsigned short)(va.y & 0xffff)) + bs2f((unsigned short)(vb.y & 0xffff));
        s3 += bs2f((unsigned short)(va.y >> 16))    + bs2f((unsigned short)(vb.y >> 16));
        s4 += bs2f((unsigned short)(va.z & 0xffff)) + bs2f((unsigned short)(vb.z & 0xffff));
        s5 += bs2f((unsigned short)(va.z >> 16))    + bs2f((unsigned short)(vb.z >> 16));
        s6 += bs2f((unsigned short)(va.w & 0xffff)) + bs2f((unsigned short)(vb.w & 0xffff));
        s7 += bs2f((unsigned short)(va.w >> 16))    + bs2f((unsigned short)(vb.w >> 16));
    }
    if (j < deg) {
        int sra = eidx[start + j];
        uint4 va = *(const uint4*)(src + (size_t)sra * DD + l * 8);
        s0 += bs2f((unsigned short)(va.x & 0xffff));
        s1 += bs2f((unsigned short)(va.x >> 16));
        s2 += bs2f((unsigned short)(va.y & 0xffff));
        s3 += bs2f((unsigned short)(va.y >> 16));
        s4 += bs2f((unsigned short)(va.z & 0xffff));
        s5 += bs2f((unsigned short)(va.z >> 16));
        s6 += bs2f((unsigned short)(va.w & 0xffff));
        s7 += bs2f((unsigned short)(va.w >> 16));
    }
    float inv = 1.0f / (float)(deg > 1 ? deg : 1);
    uint4 o;
    o.x = ((unsigned int)f2bs(s1 * inv) << 16) | f2bs(s0 * inv);
    o.y = ((unsigned int)f2bs(s3 * inv) << 16) | f2bs(s2 * inv);
    o.z = ((unsigned int)f2bs(s5 * inv) << 16) | f2bs(s4 * inv);
    o.w = ((unsigned int)f2bs(s7 * inv) << 16) | f2bs(s6 * inv);
    *(uint4*)(accb + (size_t)rr * DD + l * 8) = o;
}

// C[50000,128] = relu(postmul * concat_K(segs) @ Wt^T), bf16 MFMA, f32 out.
// A segs: up to 3 bf16 [NN][128] matrices, K = ksteps*64 (128 per segment).
// Wt: bf16 [128 n][Ktot k]. Tile: BM=128, BN=64, BK=64, 4 waves.
__global__ __launch_bounds__(256) void mfma_gemm_kernel(
    const unsigned short* __restrict__ a0, const unsigned short* __restrict__ a1,
    const unsigned short* __restrict__ a2, const unsigned short* __restrict__ Wt,
    float* __restrict__ outp, float postmul, int ksteps) {
    __shared__ unsigned char lAb[128 * 128];   // [128 rows][64 k] bf16, XOR-swizzled
    __shared__ unsigned char lBb[64 * 128];    // [64 n][64 k] bf16, XOR-swizzled

    const int tid = threadIdx.x;
    const int m0 = blockIdx.x * 128;
    const int n0 = blockIdx.y * 64;
    const int Ktot = ksteps * 64;
    const int wv = tid >> 6, lane = tid & 63;

    f32x4 acc[2][4];
    #pragma unroll
    for (int i = 0; i < 2; ++i)
        #pragma unroll
        for (int j = 0; j < 4; ++j) acc[i][j] = (f32x4)(0.f);

    for (int kt = 0; kt < ksteps; ++kt) {
        const unsigned short* As = (kt >> 1) == 0 ? a0 : (kt >> 1) == 1 ? a1 : a2;
        const int ks0 = (kt & 1) * 64;
        // stage A: 128x64 bf16 = 2048 x 8B units, 8 per thread
        #pragma unroll
        for (int i = 0; i < 8; ++i) {
            int idx = i * 256 + tid;
            int row = idx >> 4, ku = idx & 15;     // 16 units/row
            int g = m0 + row;
            unsigned long long v = 0ull;
            if (g < NN)
                v = *(const unsigned long long*)(As + (size_t)g * DD + ks0 + ku * 4);
            int byte = (row * 128 + ku * 8) ^ ((row & 7) << 4);
            *(unsigned long long*)(lAb + byte) = v;
        }
        // stage B: 64x64 bf16 = 1024 x 8B units, 4 per thread
        #pragma unroll
        for (int i = 0; i < 4; ++i) {
            int idx = i * 256 + tid;
            int n = idx >> 4, ku = idx & 15;
            unsigned long long v =
                *(const unsigned long long*)(Wt + (size_t)(n0 + n) * Ktot + kt * 64 + ku * 4);
            int byte = (n * 128 + ku * 8) ^ ((n & 7) << 4);
            *(unsigned long long*)(lBb + byte) = v;
        }
        __syncthreads();

        #pragma unroll
        for (int kk = 0; kk < 2; ++kk) {           // k-half within BK=64
            bf16x8 af[2], bfr[4];
            #pragma unroll
            for (int mi = 0; mi < 2; ++mi) {
                int row = wv * 32 + mi * 16 + (lane & 15);
                int byte = (row * 128 + kk * 64 + (lane >> 4) * 16) ^ ((row & 7) << 4);
                af[mi] = *(const bf16x8*)(lAb + byte);
            }
            #pragma unroll
            for (int ni = 0; ni < 4; ++ni) {
                int n = ni * 16 + (lane & 15);
                int byte = (n * 128 + kk * 64 + (lane >> 4) * 16) ^ ((n & 7) << 4);
                bfr[ni] = *(const bf16x8*)(lBb + byte);
            }
            #pragma unroll
            for (int mi = 0; mi < 2; ++mi)
                #pragma unroll
                for (int ni = 0; ni < 4; ++ni)
                    acc[mi][ni] = __builtin_amdgcn_mfma_f32_16x16x32_bf16(
                        af[mi], bfr[ni], acc[mi][ni], 0, 0, 0);
        }
        __syncthreads();
    }

    // epilogue: C frag mapping col=lane&15, row=(lane>>4)*4+r  [m89/m91]
    #pragma unroll
    for (int mi = 0; mi < 2; ++mi) {
        #pragma unroll
        for (int ni = 0; ni < 4; ++ni) {
            #pragma unroll
            for (int r = 0; r < 4; ++r) {
                int g = m0 + wv * 32 + mi * 16 + (lane >> 4) * 4 + r;
                if (g < NN) {
                    float v = acc[mi][ni][r] * postmul;
                    outp[(size_t)g * DD + n0 + ni * 16 + (lane & 15)] = v > 0.f ? v : 0.f;
                }
            }
        }
    }
}

extern "C" void kernel_launch(void* const* d_in, const int* in_sizes, int n_in,
                              void* d_out, int out_size, void* d_ws, size_t ws_size,
                              hipStream_t stream) {
    const float* x_user = (const float*)d_in[0];
    const float* x_item = (const float*)d_in[1];
    const float* w_rates_src   = (const float*)d_in[2];
    const float* w_rates_tgt   = (const float*)d_in[3];
    const float* w_rated_src   = (const float*)d_in[4];
    const float* w_rated_tgt   = (const float*)d_in[5];
    const float* w_follows_src = (const float*)d_in[6];
    const float* w_follows_tgt = (const float*)d_in[7];
    const int* e_rates   = (const int*)d_in[8];    // row0 src(user), row1 tgt(item)
    const int* e_rated   = (const int*)d_in[9];    // row0 src(item), row1 tgt(user)
    const int* e_follows = (const int*)d_in[10];   // row0 src(user), row1 tgt(user)

    // ---- workspace carve-up (~70 MB) ----
    char* p = (char*)d_ws;
    unsigned short* xub  = (unsigned short*)p; p += (size_t)PP * 2;
    unsigned short* xib  = (unsigned short*)p; p += (size_t)PP * 2;
    unsigned short* accb = (unsigned short*)p; p += (size_t)3 * PP * 2;  // [3][NN][128]
    unsigned short* Wu   = (unsigned short*)p; p += (size_t)128 * 384 * 2;
    unsigned short* Wi   = (unsigned short*)p; p += (size_t)128 * 256 * 2;
    int* cnt    = (int*)p; p += (size_t)3 * NN * 4;
    int* cursor = (int*)p; p += (size_t)3 * NN * 4;
    int* rowst  = (int*)p; p += (size_t)3 * NN * 4;
    int* bsum   = (int*)p; p += (size_t)64 * 4;
    unsigned short* eidx = (unsigned short*)p;               // [3*EE] u16

    float* out_user = (float*)d_out;
    float* out_item = out_user + PP;

    const int NSCAN = 3 * NN;                 // 150000
    const int NB = (NSCAN + 4095) / 4096;     // 37 scan blocks

    // rel 0: rated (tgt=user, src=item); rel 1: follows (u->u); rel 2: rates (tgt=item, src=user)
    hipMemsetAsync(cnt, 0, (size_t)6 * NN * sizeof(int), stream);
    cvtx_kernel<<<2048, 256, 0, stream>>>(x_user, x_item, xub, xib);
    wprep_kernel<<<128, 256, 0, stream>>>(w_rated_tgt, w_follows_tgt, w_rated_src,
                                          w_follows_src, w_rates_tgt, w_rates_src,
                                          Wu, Wi);
    const int EB3 = (3 * EE + 255) / 256;
    hist3_kernel<<<EB3, 256, 0, stream>>>(e_rated + EE, e_follows + EE, e_rates + EE, cnt);
    scan_part_kernel<<<NB, 256, 0, stream>>>(cnt, rowst, bsum, NSCAN);
    scan_tops_kernel<<<1, 64, 0, stream>>>(bsum, NB);
    scan_add_kernel<<<(NSCAN + 255) / 256, 256, 0, stream>>>(rowst, bsum, NSCAN);
    place3_kernel<<<EB3, 256, 0, stream>>>(e_rated, e_rated + EE,
                                           e_follows, e_follows + EE,
                                           e_rates, e_rates + EE,
                                           rowst, cursor, eidx);
    gather3_kernel<<<(3 * NN * 16 + 255) / 256, 256, 0, stream>>>(
        xub, xib, rowst, cnt, eidx, accb);

    // out_user = relu(0.5*( x_user@(Wrt+Wft) + accR@Wrs + accF@Wfs ))
    dim3 gg((NN + 127) / 128, 2);
    mfma_gemm_kernel<<<gg, 256, 0, stream>>>(xub, accb, accb + PP, Wu,
                                             out_user, 0.5f, 6);
    // out_item = relu( x_item@Wit + accI@Wis )
    mfma_gemm_kernel<<<gg, 256, 0, stream>>>(xib, accb + 2 * PP, nullptr, Wi,
                                             out_item, 1.0f, 4);
}

// Round 8
// 237.885 us; speedup vs baseline: 4.2356x; 1.2203x over previous
//
#include <hip/hip_runtime.h>
#include <hip/hip_bf16.h>

constexpr int NN = 50000;      // nodes per type
constexpr int DD = 128;        // feature dim
constexpr int EE = 600000;     // edges per relation
constexpr long long PP = (long long)NN * DD;   // 6,400,000 elems per [N,128]
constexpr int NTGT = 3 * NN;               // 150000 targets across relations
constexpr int SLICE_W = (NTGT + 7) / 8;    // 18750 targets per XCD slice

typedef __bf16 bf16x8 __attribute__((ext_vector_type(8)));
typedef float f32x4 __attribute__((ext_vector_type(4)));

__device__ inline unsigned short f2bs(float x) {
    __hip_bfloat16 b = __float2bfloat16(x);
    return *reinterpret_cast<unsigned short*>(&b);
}
__device__ inline float bs2f(unsigned short u) {
    union { float f; unsigned int u; } x; x.u = ((unsigned int)u) << 16; return x.f;
}

// f32 -> bf16 copies of x_user / x_item
__global__ void cvtx_kernel(const float* __restrict__ xu, const float* __restrict__ xi,
                            unsigned short* __restrict__ xub, unsigned short* __restrict__ xib) {
    const int total = (int)(PP / 4);
    for (int i = blockIdx.x * blockDim.x + threadIdx.x; i < total;
         i += gridDim.x * blockDim.x) {
        float4 a = ((const float4*)xu)[i];
        float4 b = ((const float4*)xi)[i];
        ushort4 oa, ob;
        oa.x = f2bs(a.x); oa.y = f2bs(a.y); oa.z = f2bs(a.z); oa.w = f2bs(a.w);
        ob.x = f2bs(b.x); ob.y = f2bs(b.y); ob.z = f2bs(b.z); ob.w = f2bs(b.w);
        ((ushort4*)xub)[i] = oa;
        ((ushort4*)xib)[i] = ob;
    }
}

// Transposed bf16 weights: Wu[n][384] = [Wrt+Wft ; Wrs ; Wfs]^T, Wi[n][256] = [Wit ; Wis]^T
__global__ void wprep_kernel(const float* __restrict__ wrt, const float* __restrict__ wft,
                             const float* __restrict__ wrs, const float* __restrict__ wfs,
                             const float* __restrict__ wit, const float* __restrict__ wis,
                             unsigned short* __restrict__ Wu, unsigned short* __restrict__ Wi) {
    int n = blockIdx.x;   // 0..127
    for (int k = threadIdx.x; k < 384; k += blockDim.x) {
        int seg = k >> 7, ks = k & 127;
        float v = (seg == 0) ? (wrt[ks * 128 + n] + wft[ks * 128 + n])
                : (seg == 1) ? wrs[ks * 128 + n] : wfs[ks * 128 + n];
        Wu[n * 384 + k] = f2bs(v);
    }
    for (int k = threadIdx.x; k < 256; k += blockDim.x) {
        int seg = k >> 7, ks = k & 127;
        float v = (seg == 0) ? wit[ks * 128 + n] : wis[ks * 128 + n];
        Wi[n * 256 + k] = f2bs(v);
    }
}

// histogram over all 3 relations; also records each edge's within-target
// ordinal (the atomic's return) so placement needs no atomics.
__global__ void hist3_kernel(const int* __restrict__ t0, const int* __restrict__ t1,
                             const int* __restrict__ t2, int* __restrict__ cnt,
                             int* __restrict__ pos) {
    int idx = blockIdx.x * blockDim.x + threadIdx.x;
    if (idx >= 3 * EE) return;
    int rel = idx / EE;
    int e = idx - rel * EE;
    const int* tp = (rel == 0) ? t0 : (rel == 1) ? t1 : t2;
    pos[idx] = atomicAdd(&cnt[rel * NN + tp[e]], 1);
}

// ---- 3-stage hierarchical exclusive scan over n=150000 entries ----
__global__ __launch_bounds__(256) void scan_part_kernel(
    const int* __restrict__ cnt, int* __restrict__ rowst,
    int* __restrict__ bsum, int n) {
    const int tid = threadIdx.x;
    const int base = blockIdx.x * 4096 + tid * 16;
    int v[16];
    #pragma unroll
    for (int i = 0; i < 16; ++i) {
        int g = base + i;
        v[i] = (g < n) ? cnt[g] : 0;
    }
    int s = 0;
    #pragma unroll
    for (int i = 0; i < 16; ++i) s += v[i];
    const int lane = tid & 63, wv = tid >> 6;
    int incl = s;
    #pragma unroll
    for (int d = 1; d < 64; d <<= 1) {
        int u = __shfl_up(incl, d, 64);
        if (lane >= d) incl += u;
    }
    __shared__ int wsum[4];
    if (lane == 63) wsum[wv] = incl;
    __syncthreads();
    int woff = 0;
    for (int w = 0; w < wv; ++w) woff += wsum[w];
    int run = woff + incl - s;                 // exclusive prefix for this thread
    #pragma unroll
    for (int i = 0; i < 16; ++i) {
        int g = base + i;
        if (g < n) rowst[g] = run;
        run += v[i];
    }
    if (tid == 255) bsum[blockIdx.x] = woff + incl;   // block total
}

__global__ void scan_tops_kernel(int* __restrict__ bsum, int nb) {
    if (threadIdx.x == 0 && blockIdx.x == 0) {
        int run = 0;
        for (int i = 0; i < nb; ++i) { int v = bsum[i]; bsum[i] = run; run += v; }
    }
}

__global__ void scan_add_kernel(int* __restrict__ rowst, const int* __restrict__ bsum,
                                int n) {
    int i = blockIdx.x * blockDim.x + threadIdx.x;
    if (i < n) rowst[i] += bsum[i >> 12];
}

// XCD-sliced, atomic-free placement. Block b handles target slice (b&7);
// with round-robin workgroup->XCD dispatch all writers of a slice share one
// XCD's L2 (~450KB slice stays resident; each 64B line written back once),
// killing the cross-XCD line-thrash that made WRITE_SIZE ~98MB.
__global__ __launch_bounds__(256) void place3_kernel(
    const int* __restrict__ s0, const int* __restrict__ t0,
    const int* __restrict__ s1, const int* __restrict__ t1,
    const int* __restrict__ s2, const int* __restrict__ t2,
    const int* __restrict__ rowst, const int* __restrict__ pos,
    unsigned short* __restrict__ eidx) {
    const int slice = blockIdx.x & 7;
    const int tlo = slice * SLICE_W;
    const int thi = (tlo + SLICE_W < NTGT) ? tlo + SLICE_W : NTGT;
    const int stride = (gridDim.x >> 3) * 256;
    for (int idx = (blockIdx.x >> 3) * 256 + threadIdx.x; idx < 3 * EE;
         idx += stride) {
        int rel = idx / EE;
        int e = idx - rel * EE;
        const int* tp = (rel == 0) ? t0 : (rel == 1) ? t1 : t2;
        int t = rel * NN + tp[e];
        if (t < tlo || t >= thi) continue;
        const int* sp = (rel == 0) ? s0 : (rel == 1) ? s1 : s2;
        eidx[rowst[t] + pos[idx]] = (unsigned short)sp[e];
    }
}

// 16 lanes per target row (4 rows per wave), 16B/lane loads, degree loop
// unrolled x2 -> up to 8 outstanding 256B row-reads per wave (MLP).
__global__ __launch_bounds__(256) void gather3_kernel(
    const unsigned short* __restrict__ xub, const unsigned short* __restrict__ xib,
    const int* __restrict__ rowst, const int* __restrict__ cnt,
    const unsigned short* __restrict__ eidx, unsigned short* __restrict__ accb) {
    int rr = (int)((blockIdx.x * blockDim.x + threadIdx.x) >> 4);
    int l = threadIdx.x & 15;               // lane within 16-lane row group
    if (rr >= 3 * NN) return;
    int rel = rr / NN;                      // 0: rated(src=item) 1: follows 2: rates
    const unsigned short* src = (rel == 0) ? xib : xub;
    int start = rowst[rr], deg = cnt[rr];
    float s0 = 0.f, s1 = 0.f, s2 = 0.f, s3 = 0.f,
          s4 = 0.f, s5 = 0.f, s6 = 0.f, s7 = 0.f;
    int j = 0;
    for (; j + 2 <= deg; j += 2) {
        int sra = eidx[start + j];
        int srb = eidx[start + j + 1];
        uint4 va = *(const uint4*)(src + (size_t)sra * DD + l * 8);
        uint4 vb = *(const uint4*)(src + (size_t)srb * DD + l * 8);
        s0 += bs2f((unsigned short)(va.x & 0xffff)) + bs2f((unsigned short)(vb.x & 0xffff));
        s1 += bs2f((unsigned short)(va.x >> 16))    + bs2f((unsigned short)(vb.x >> 16));
        s2 += bs2f((unsigned short)(va.y & 0xffff)) + bs2f((unsigned short)(vb.y & 0xffff));
        s3 += bs2f((unsigned short)(va.y >> 16))    + bs2f((unsigned short)(vb.y >> 16));
        s4 += bs2f((unsigned short)(va.z & 0xffff)) + bs2f((unsigned short)(vb.z & 0xffff));
        s5 += bs2f((unsigned short)(va.z >> 16))    + bs2f((unsigned short)(vb.z >> 16));
        s6 += bs2f((unsigned short)(va.w & 0xffff)) + bs2f((unsigned short)(vb.w & 0xffff));
        s7 += bs2f((unsigned short)(va.w >> 16))    + bs2f((unsigned short)(vb.w >> 16));
    }
    if (j < deg) {
        int sra = eidx[start + j];
        uint4 va = *(const uint4*)(src + (size_t)sra * DD + l * 8);
        s0 += bs2f((unsigned short)(va.x & 0xffff));
        s1 += bs2f((unsigned short)(va.x >> 16));
        s2 += bs2f((unsigned short)(va.y & 0xffff));
        s3 += bs2f((unsigned short)(va.y >> 16));
        s4 += bs2f((unsigned short)(va.z & 0xffff));
        s5 += bs2f((unsigned short)(va.z >> 16));
        s6 += bs2f((unsigned short)(va.w & 0xffff));
        s7 += bs2f((unsigned short)(va.w >> 16));
    }
    float inv = 1.0f / (float)(deg > 1 ? deg : 1);
    uint4 o;
    o.x = ((unsigned int)f2bs(s1 * inv) << 16) | f2bs(s0 * inv);
    o.y = ((unsigned int)f2bs(s3 * inv) << 16) | f2bs(s2 * inv);
    o.z = ((unsigned int)f2bs(s5 * inv) << 16) | f2bs(s4 * inv);
    o.w = ((unsigned int)f2bs(s7 * inv) << 16) | f2bs(s6 * inv);
    *(uint4*)(accb + (size_t)rr * DD + l * 8) = o;
}

// C[50000,128] = relu(postmul * concat_K(segs) @ Wt^T), bf16 MFMA, f32 out.
// A segs: up to 3 bf16 [NN][128] matrices, K = ksteps*64 (128 per segment).
// Wt: bf16 [128 n][Ktot k]. Tile: BM=128, BN=64, BK=64, 4 waves.
__global__ __launch_bounds__(256) void mfma_gemm_kernel(
    const unsigned short* __restrict__ a0, const unsigned short* __restrict__ a1,
    const unsigned short* __restrict__ a2, const unsigned short* __restrict__ Wt,
    float* __restrict__ outp, float postmul, int ksteps) {
    __shared__ unsigned char lAb[128 * 128];   // [128 rows][64 k] bf16, XOR-swizzled
    __shared__ unsigned char lBb[64 * 128];    // [64 n][64 k] bf16, XOR-swizzled

    const int tid = threadIdx.x;
    const int m0 = blockIdx.x * 128;
    const int n0 = blockIdx.y * 64;
    const int Ktot = ksteps * 64;
    const int wv = tid >> 6, lane = tid & 63;

    f32x4 acc[2][4];
    #pragma unroll
    for (int i = 0; i < 2; ++i)
        #pragma unroll
        for (int j = 0; j < 4; ++j) acc[i][j] = (f32x4)(0.f);

    for (int kt = 0; kt < ksteps; ++kt) {
        const unsigned short* As = (kt >> 1) == 0 ? a0 : (kt >> 1) == 1 ? a1 : a2;
        const int ks0 = (kt & 1) * 64;
        // stage A: 128x64 bf16 = 2048 x 8B units, 8 per thread
        #pragma unroll
        for (int i = 0; i < 8; ++i) {
            int idx = i * 256 + tid;
            int row = idx >> 4, ku = idx & 15;     // 16 units/row
            int g = m0 + row;
            unsigned long long v = 0ull;
            if (g < NN)
                v = *(const unsigned long long*)(As + (size_t)g * DD + ks0 + ku * 4);
            int byte = (row * 128 + ku * 8) ^ ((row & 7) << 4);
            *(unsigned long long*)(lAb + byte) = v;
        }
        // stage B: 64x64 bf16 = 1024 x 8B units, 4 per thread
        #pragma unroll
        for (int i = 0; i < 4; ++i) {
            int idx = i * 256 + tid;
            int n = idx >> 4, ku = idx & 15;
            unsigned long long v =
                *(const unsigned long long*)(Wt + (size_t)(n0 + n) * Ktot + kt * 64 + ku * 4);
            int byte = (n * 128 + ku * 8) ^ ((n & 7) << 4);
            *(unsigned long long*)(lBb + byte) = v;
        }
        __syncthreads();

        #pragma unroll
        for (int kk = 0; kk < 2; ++kk) {           // k-half within BK=64
            bf16x8 af[2], bfr[4];
            #pragma unroll
            for (int mi = 0; mi < 2; ++mi) {
                int row = wv * 32 + mi * 16 + (lane & 15);
                int byte = (row * 128 + kk * 64 + (lane >> 4) * 16) ^ ((row & 7) << 4);
                af[mi] = *(const bf16x8*)(lAb + byte);
            }
            #pragma unroll
            for (int ni = 0; ni < 4; ++ni) {
                int n = ni * 16 + (lane & 15);
                int byte = (n * 128 + kk * 64 + (lane >> 4) * 16) ^ ((n & 7) << 4);
                bfr[ni] = *(const bf16x8*)(lBb + byte);
            }
            #pragma unroll
            for (int mi = 0; mi < 2; ++mi)
                #pragma unroll
                for (int ni = 0; ni < 4; ++ni)
                    acc[mi][ni] = __builtin_amdgcn_mfma_f32_16x16x32_bf16(
                        af[mi], bfr[ni], acc[mi][ni], 0, 0, 0);
        }
        __syncthreads();
    }

    // epilogue: C frag mapping col=lane&15, row=(lane>>4)*4+r  [m89/m91]
    #pragma unroll
    for (int mi = 0; mi < 2; ++mi) {
        #pragma unroll
        for (int ni = 0; ni < 4; ++ni) {
            #pragma unroll
            for (int r = 0; r < 4; ++r) {
                int g = m0 + wv * 32 + mi * 16 + (lane >> 4) * 4 + r;
                if (g < NN) {
                    float v = acc[mi][ni][r] * postmul;
                    outp[(size_t)g * DD + n0 + ni * 16 + (lane & 15)] = v > 0.f ? v : 0.f;
                }
            }
        }
    }
}

extern "C" void kernel_launch(void* const* d_in, const int* in_sizes, int n_in,
                              void* d_out, int out_size, void* d_ws, size_t ws_size,
                              hipStream_t stream) {
    const float* x_user = (const float*)d_in[0];
    const float* x_item = (const float*)d_in[1];
    const float* w_rates_src   = (const float*)d_in[2];
    const float* w_rates_tgt   = (const float*)d_in[3];
    const float* w_rated_src   = (const float*)d_in[4];
    const float* w_rated_tgt   = (const float*)d_in[5];
    const float* w_follows_src = (const float*)d_in[6];
    const float* w_follows_tgt = (const float*)d_in[7];
    const int* e_rates   = (const int*)d_in[8];    // row0 src(user), row1 tgt(item)
    const int* e_rated   = (const int*)d_in[9];    // row0 src(item), row1 tgt(user)
    const int* e_follows = (const int*)d_in[10];   // row0 src(user), row1 tgt(user)

    // ---- workspace carve-up (~77 MB) ----
    char* p = (char*)d_ws;
    unsigned short* xub  = (unsigned short*)p; p += (size_t)PP * 2;
    unsigned short* xib  = (unsigned short*)p; p += (size_t)PP * 2;
    unsigned short* accb = (unsigned short*)p; p += (size_t)3 * PP * 2;  // [3][NN][128]
    unsigned short* Wu   = (unsigned short*)p; p += (size_t)128 * 384 * 2;
    unsigned short* Wi   = (unsigned short*)p; p += (size_t)128 * 256 * 2;
    int* cnt    = (int*)p; p += (size_t)NTGT * 4;
    int* rowst  = (int*)p; p += (size_t)NTGT * 4;
    int* bsum   = (int*)p; p += (size_t)64 * 4;
    int* pos    = (int*)p; p += (size_t)3 * EE * 4;          // [3*EE] ordinals
    unsigned short* eidx = (unsigned short*)p;               // [3*EE] u16

    float* out_user = (float*)d_out;
    float* out_item = out_user + PP;

    const int NB = (NTGT + 4095) / 4096;      // 37 scan blocks

    // rel 0: rated (tgt=user, src=item); rel 1: follows (u->u); rel 2: rates (tgt=item, src=user)
    hipMemsetAsync(cnt, 0, (size_t)NTGT * sizeof(int), stream);
    cvtx_kernel<<<2048, 256, 0, stream>>>(x_user, x_item, xub, xib);
    wprep_kernel<<<128, 256, 0, stream>>>(w_rated_tgt, w_follows_tgt, w_rated_src,
                                          w_follows_src, w_rates_tgt, w_rates_src,
                                          Wu, Wi);
    const int EB3 = (3 * EE + 255) / 256;
    hist3_kernel<<<EB3, 256, 0, stream>>>(e_rated + EE, e_follows + EE, e_rates + EE,
                                          cnt, pos);
    scan_part_kernel<<<NB, 256, 0, stream>>>(cnt, rowst, bsum, NTGT);
    scan_tops_kernel<<<1, 64, 0, stream>>>(bsum, NB);
    scan_add_kernel<<<(NTGT + 255) / 256, 256, 0, stream>>>(rowst, bsum, NTGT);
    place3_kernel<<<4096, 256, 0, stream>>>(e_rated, e_rated + EE,
                                            e_follows, e_follows + EE,
                                            e_rates, e_rates + EE,
                                            rowst, pos, eidx);
    gather3_kernel<<<(3 * NN * 16 + 255) / 256, 256, 0, stream>>>(
        xub, xib, rowst, cnt, eidx, accb);

    // out_user = relu(0.5*( x_user@(Wrt+Wft) + accR@Wrs + accF@Wfs ))
    dim3 gg((NN + 127) / 128, 2);
    mfma_gemm_kernel<<<gg, 256, 0, stream>>>(xub, accb, accb + PP, Wu,
                                             out_user, 0.5f, 6);
    // out_item = relu( x_item@Wit + accI@Wis )
    mfma_gemm_kernel<<<gg, 256, 0, stream>>>(xib, accb + 2 * PP, nullptr, Wi,
                                             out_item, 1.0f, 4);
}